// Round 5
// baseline (116.964 us; speedup 1.0000x reference)
//
#include <hip/hip_runtime.h>

#define T_ 16
#define B_ 32
#define N_ 4096
#define NT 20
#define F_ 25
#define H_ 8
#define HID_ 128
#define PSTR 9               // padded LDS pool stride (spreads banks across ty rows)
#define SEGF_ (NT*H_)        // 160
#define BT 512               // threads per block; one block per (t,b)
#define NSUB (N_/BT)         // 8 sub-chunks of 512 points
#define CF (BT*F_)           // 12800 floats per sub-chunk

// bf16 pack/unpack (values nonneg finite: relu outputs)
__device__ __forceinline__ unsigned f2bf(float x) {
  unsigned u = __float_as_uint(x);
  u += 0x7fffu + ((u >> 16) & 1u);     // round-to-nearest-even
  return u >> 16;
}
__device__ __forceinline__ float bf2f(unsigned s) { return __uint_as_float(s << 16); }

// Tiny fully-unrolled MLP layer: out = relu(in @ W + b), W is (NI x 8) row-major.
// W/b wave-uniform + compile-time indices -> scalar loads.
template<int NI>
__device__ __forceinline__ void layer(const float* in, const float* __restrict__ W,
                                      const float* __restrict__ b, float* out) {
#pragma unroll
  for (int j = 0; j < H_; j++) {
    float a = b[j];
#pragma unroll
    for (int f = 0; f < NI; f++) a = fmaf(in[f], W[f*H_ + j], a);
    out[j] = fmaxf(a, 0.0f);
  }
}

// One block per (t,b): 8x-unrolled point loop keeps h3 (bf16-packed) + ty in
// registers across the pool1 barrier. Single kernel, no workspace.
extern "C" __global__ __launch_bounds__(BT, 4)
void kFused(const float* __restrict__ pts,
            const float* __restrict__ W1, const float* __restrict__ b1,
            const float* __restrict__ W2, const float* __restrict__ b2,
            const float* __restrict__ W3, const float* __restrict__ b3,
            const float* __restrict__ W4, const float* __restrict__ b4,
            const float* __restrict__ W5, const float* __restrict__ b5,
            const float* __restrict__ W6, const float* __restrict__ b6,
            const float* __restrict__ Wout, const float* __restrict__ bout,
            float* __restrict__ out)
{
  __shared__ float xs[CF];            // 51.2 KB point staging
  __shared__ int lp1[NT*PSTR];        // pool1 (nonneg float bits: int max == float max)
  __shared__ int lp2[NT*PSTR];        // pool2
  const int tid = threadIdx.x;
  const int tb = blockIdx.x;
  if (tid < NT*PSTR) { lp1[tid] = 0; lp2[tid] = 0; }

  const float* base = pts + (size_t)tb * (N_*F_);

  // prologue: issue chunk-0 loads (coalesced: 6 float4 + 1 dword per thread)
  float4 r[6]; float rt;
  {
    const float4* g4 = (const float4*)base;
#pragma unroll
    for (int k = 0; k < 6; k++) r[k] = g4[tid + k*BT];
    rt = base[6*4*BT + tid];
  }

  uint4 h3p[8];                        // bf16x8 per point, statically indexed
  int   tyv[8];

  // ================= Phase 1: MLP1 + pool1 =================
#pragma unroll
  for (int s = 0; s < NSUB; s++) {
    if (s) __syncthreads();            // previous compute done reading xs
    {
      float4* x4 = (float4*)xs;
#pragma unroll
      for (int k = 0; k < 6; k++) x4[tid + k*BT] = r[k];
      xs[6*4*BT + tid] = rt;
    }
    __syncthreads();                   // xs ready
    if (s < NSUB-1) {                  // prefetch next chunk; hides under compute
      const float* gn = base + (s+1)*CF;
      const float4* gn4 = (const float4*)gn;
#pragma unroll
      for (int k = 0; k < 6; k++) r[k] = gn4[tid + k*BT];
      rt = gn[6*4*BT + tid];
    }

    float xv[F_];
#pragma unroll
    for (int f = 0; f < F_; f++) xv[f] = xs[tid*F_ + f];  // stride-25: free 2-way alias

    int ty = 0; float best = xv[4];
#pragma unroll
    for (int k = 1; k < NT; k++) if (xv[4+k] > best) { best = xv[4+k]; ty = k; }
    const bool valid = (xv[F_-1] != 0.0f);

    float t1[H_], t2[H_];
    layer<F_>(xv, W1, b1, t1);
    layer<H_>(t1, W2, b2, t2);
    layer<H_>(t2, W3, b3, t1);         // t1 = h3
    if (!valid) {
#pragma unroll
      for (int j = 0; j < H_; j++) t1[j] = 0.0f;
    }

    h3p[s].x = f2bf(t1[0]) | (f2bf(t1[1]) << 16);
    h3p[s].y = f2bf(t1[2]) | (f2bf(t1[3]) << 16);
    h3p[s].z = f2bf(t1[4]) | (f2bf(t1[5]) << 16);
    h3p[s].w = f2bf(t1[6]) | (f2bf(t1[7]) << 16);
    tyv[s] = valid ? ty : -1;
    if (valid) {
#pragma unroll
      for (int j = 0; j < H_; j++)
        atomicMax(&lp1[ty*PSTR + j], __float_as_int(t1[j]));
    }
  }
  __syncthreads();                     // pool1 final

  // ================= Phase 2: concat + MLP2 + pool2 (all in-reg/LDS) =========
#pragma unroll
  for (int s = 0; s < NSUB; s++) {
    const int ty = tyv[s];
    if (ty >= 0) {                     // invalid -> zero contribution -> skip
      float x16[2*H_];
      x16[0] = bf2f(h3p[s].x & 0xffffu); x16[1] = bf2f(h3p[s].x >> 16);
      x16[2] = bf2f(h3p[s].y & 0xffffu); x16[3] = bf2f(h3p[s].y >> 16);
      x16[4] = bf2f(h3p[s].z & 0xffffu); x16[5] = bf2f(h3p[s].z >> 16);
      x16[6] = bf2f(h3p[s].w & 0xffffu); x16[7] = bf2f(h3p[s].w >> 16);
#pragma unroll
      for (int j = 0; j < H_; j++) x16[H_+j] = __int_as_float(lp1[ty*PSTR + j]);
      float t1[H_], t2[H_];
      layer<2*H_>(x16, W4, b4, t1);
      layer<H_>(t1, W5, b5, t2);
      layer<H_>(t2, W6, b6, t1);
#pragma unroll
      for (int j = 0; j < H_; j++)
        atomicMax(&lp2[ty*PSTR + j], __float_as_int(t1[j]));
    }
  }
  __syncthreads();                     // pool2 final

  // ================= Phase 3: out[tb,:] = relu(pooled2 @ Wout + bout) ========
  if (tid < HID_) {
    float a = bout[tid];
#pragma unroll 4
    for (int k = 0; k < SEGF_; k++) {
      const float v = __int_as_float(lp2[(k >> 3)*PSTR + (k & 7)]);
      a = fmaf(v, Wout[k*HID_ + tid], a);
    }
    out[tb*HID_ + tid] = fmaxf(a, 0.0f);
  }
}

extern "C" void kernel_launch(void* const* d_in, const int* in_sizes, int n_in,
                              void* d_out, int out_size, void* d_ws, size_t ws_size,
                              hipStream_t stream) {
  const float* pts  = (const float*)d_in[0];
  const float* W1   = (const float*)d_in[1];  const float* b1 = (const float*)d_in[2];
  const float* W2   = (const float*)d_in[3];  const float* b2 = (const float*)d_in[4];
  const float* W3   = (const float*)d_in[5];  const float* b3 = (const float*)d_in[6];
  const float* W4   = (const float*)d_in[7];  const float* b4 = (const float*)d_in[8];
  const float* W5   = (const float*)d_in[9];  const float* b5 = (const float*)d_in[10];
  const float* W6   = (const float*)d_in[11]; const float* b6 = (const float*)d_in[12];
  const float* Wout = (const float*)d_in[13]; const float* bout = (const float*)d_in[14];
  float* out = (float*)d_out;

  kFused<<<T_*B_, BT, 0, stream>>>(pts, W1, b1, W2, b2, W3, b3,
                                   W4, b4, W5, b5, W6, b6, Wout, bout, out);
}

// Round 6
// 67.129 us; speedup vs baseline: 1.7424x; 1.7424x over previous
//
#include <hip/hip_runtime.h>

#define T_ 16
#define B_ 32
#define N_ 4096
#define NT 20
#define F_ 25
#define H_ 8
#define HID_ 128
#define PSTR 9               // padded LDS pool stride (spreads banks across ty rows)
#define SEGF_ (NT*H_)        // 160
#define BT 512               // threads per block; one block per (t,b)
#define NSUB (N_/BT)         // 8 chunks of 512 points
#define CF (BT*F_)           // 12800 floats per chunk

typedef __attribute__((address_space(1))) const void GV;
typedef __attribute__((address_space(3))) void LV;

// async global->LDS, no VGPR staging. Linear lane pattern (wave-uniform base + lane*16).
__device__ __forceinline__ void g2l16(const float* g, float* l) {
  __builtin_amdgcn_global_load_lds((GV*)g, (LV*)l, 16, 0, 0);
}
__device__ __forceinline__ void g2l4(const float* g, float* l) {
  __builtin_amdgcn_global_load_lds((GV*)g, (LV*)l, 4, 0, 0);
}

// bf16 pack/unpack (values nonneg finite: relu outputs)
__device__ __forceinline__ unsigned f2bf(float x) {
  unsigned u = __float_as_uint(x);
  u += 0x7fffu + ((u >> 16) & 1u);
  return u >> 16;
}
__device__ __forceinline__ float bf2f(unsigned s) { return __uint_as_float(s << 16); }

// Tiny fully-unrolled MLP layer: out = relu(in @ W + b), W is (NI x 8) row-major.
template<int NI>
__device__ __forceinline__ void layer(const float* in, const float* __restrict__ W,
                                      const float* __restrict__ b, float* out) {
#pragma unroll
  for (int j = 0; j < H_; j++) {
    float a = b[j];
#pragma unroll
    for (int f = 0; f < NI; f++) a = fmaf(in[f], W[f*H_ + j], a);
    out[j] = fmaxf(a, 0.0f);
  }
}

// One block per (t,b). Phase1: stream 8 chunks via global_load_lds, MLP1, LDS pool1,
// h3 packed bf16 in registers (STATIC indices via macros). Phase2: MLP2 + LDS pool2.
// Phase3: fused 160x128 GEMV. Single dispatch, no workspace, no global atomics.
extern "C" __global__ __launch_bounds__(BT, 4)
void kFused(const float* __restrict__ pts,
            const float* __restrict__ W1, const float* __restrict__ b1,
            const float* __restrict__ W2, const float* __restrict__ b2,
            const float* __restrict__ W3, const float* __restrict__ b3,
            const float* __restrict__ W4, const float* __restrict__ b4,
            const float* __restrict__ W5, const float* __restrict__ b5,
            const float* __restrict__ W6, const float* __restrict__ b6,
            const float* __restrict__ Wout, const float* __restrict__ bout,
            float* __restrict__ out)
{
  __shared__ float xs[CF];            // 51.2 KB single staging buffer
  __shared__ int lp1[NT*PSTR];        // pools: nonneg float bits, int max == float max
  __shared__ int lp2[NT*PSTR];
  const int tid = threadIdx.x;
  const int tb = blockIdx.x;
  if (tid < NT*PSTR) { lp1[tid] = 0; lp2[tid] = 0; }

  const float* base = pts + (size_t)tb * (N_*F_);

#define ISSUE(S)                                                         \
  {                                                                      \
    const float* gc = base + (S)*CF;                                     \
    _Pragma("unroll")                                                    \
    for (int k = 0; k < 6; k++)                                          \
      g2l16(gc + (tid + k*BT)*4, xs + (tid + k*BT)*4);                   \
    g2l4(gc + 6*4*BT + tid, xs + 6*4*BT + tid);                          \
  }

  uint4 h3p[NSUB];                     // bf16x8 per point — literal indices only
  int   tyv[NSUB];

  ISSUE(0)

#define PH1(S)                                                           \
  {                                                                      \
    __syncthreads();  /* drains vmcnt -> chunk S in xs; lp zero seen */  \
    float xv[F_];                                                        \
    _Pragma("unroll")                                                    \
    for (int f = 0; f < F_; f++) xv[f] = xs[tid*F_ + f];                 \
    __syncthreads();  /* all reads done -> xs reusable */                \
    if ((S) < NSUB-1) ISSUE((S)+1)                                       \
    int ty = 0; float best = xv[4];                                      \
    _Pragma("unroll")                                                    \
    for (int k = 1; k < NT; k++)                                         \
      if (xv[4+k] > best) { best = xv[4+k]; ty = k; }                    \
    const bool valid = (xv[F_-1] != 0.0f);                               \
    float t1[H_], t2[H_];                                                \
    layer<F_>(xv, W1, b1, t1);                                           \
    layer<H_>(t1, W2, b2, t2);                                           \
    layer<H_>(t2, W3, b3, t1);                                           \
    if (!valid) {                                                        \
      _Pragma("unroll")                                                  \
      for (int j = 0; j < H_; j++) t1[j] = 0.0f;                         \
    }                                                                    \
    h3p[S].x = f2bf(t1[0]) | (f2bf(t1[1]) << 16);                        \
    h3p[S].y = f2bf(t1[2]) | (f2bf(t1[3]) << 16);                        \
    h3p[S].z = f2bf(t1[4]) | (f2bf(t1[5]) << 16);                        \
    h3p[S].w = f2bf(t1[6]) | (f2bf(t1[7]) << 16);                        \
    tyv[S] = valid ? ty : -1;                                            \
    if (valid) {                                                         \
      _Pragma("unroll")                                                  \
      for (int j = 0; j < H_; j++)                                       \
        atomicMax(&lp1[ty*PSTR + j], __float_as_int(t1[j]));             \
    }                                                                    \
  }

  PH1(0) PH1(1) PH1(2) PH1(3) PH1(4) PH1(5) PH1(6) PH1(7)

  __syncthreads();                     // pool1 final

#define PH2(S)                                                           \
  {                                                                      \
    const int ty = tyv[S];                                               \
    if (ty >= 0) {                                                       \
      float x16[2*H_];                                                   \
      x16[0] = bf2f(h3p[S].x & 0xffffu); x16[1] = bf2f(h3p[S].x >> 16);  \
      x16[2] = bf2f(h3p[S].y & 0xffffu); x16[3] = bf2f(h3p[S].y >> 16);  \
      x16[4] = bf2f(h3p[S].z & 0xffffu); x16[5] = bf2f(h3p[S].z >> 16);  \
      x16[6] = bf2f(h3p[S].w & 0xffffu); x16[7] = bf2f(h3p[S].w >> 16);  \
      _Pragma("unroll")                                                  \
      for (int j = 0; j < H_; j++)                                       \
        x16[H_+j] = __int_as_float(lp1[ty*PSTR + j]);                    \
      float t1[H_], t2[H_];                                              \
      layer<2*H_>(x16, W4, b4, t1);                                      \
      layer<H_>(t1, W5, b5, t2);                                         \
      layer<H_>(t2, W6, b6, t1);                                         \
      _Pragma("unroll")                                                  \
      for (int j = 0; j < H_; j++)                                       \
        atomicMax(&lp2[ty*PSTR + j], __float_as_int(t1[j]));             \
    }                                                                    \
  }

  PH2(0) PH2(1) PH2(2) PH2(3) PH2(4) PH2(5) PH2(6) PH2(7)

  __syncthreads();                     // pool2 final

  // ---- Phase 3: out[tb,:] = relu(pooled2 @ Wout + bout) ----
  if (tid < HID_) {
    float a = bout[tid];
#pragma unroll 4
    for (int k = 0; k < SEGF_; k++) {
      const float v = __int_as_float(lp2[(k >> 3)*PSTR + (k & 7)]);
      a = fmaf(v, Wout[k*HID_ + tid], a);
    }
    out[tb*HID_ + tid] = fmaxf(a, 0.0f);
  }
#undef ISSUE
#undef PH1
#undef PH2
}

extern "C" void kernel_launch(void* const* d_in, const int* in_sizes, int n_in,
                              void* d_out, int out_size, void* d_ws, size_t ws_size,
                              hipStream_t stream) {
  const float* pts  = (const float*)d_in[0];
  const float* W1   = (const float*)d_in[1];  const float* b1 = (const float*)d_in[2];
  const float* W2   = (const float*)d_in[3];  const float* b2 = (const float*)d_in[4];
  const float* W3   = (const float*)d_in[5];  const float* b3 = (const float*)d_in[6];
  const float* W4   = (const float*)d_in[7];  const float* b4 = (const float*)d_in[8];
  const float* W5   = (const float*)d_in[9];  const float* b5 = (const float*)d_in[10];
  const float* W6   = (const float*)d_in[11]; const float* b6 = (const float*)d_in[12];
  const float* Wout = (const float*)d_in[13]; const float* bout = (const float*)d_in[14];
  float* out = (float*)d_out;

  kFused<<<T_*B_, BT, 0, stream>>>(pts, W1, b1, W2, b2, W3, b3,
                                   W4, b4, W5, b5, W6, b6, Wout, bout, out);
}